// Round 12
// baseline (133.618 us; speedup 1.0000x reference)
//
#include <hip/hip_runtime.h>
#include <hip/hip_bf16.h>

// CrossAttention fused pipeline, MI355X (gfx950)
// B=2, N=160, D=4096, H=4, DH=1024, SCALE=1/32 (applied twice)
//
// R12: weight-streaming GEMM with compiler-tracked loads only.
// W fetched in 1 KB-contiguous wave-instructions (lane x f32x4 = one W row)
// into REGISTERS (compiler inserts fine-grained vmcnt on use - R7/R11 lesson:
// manual vmcnt + global_load_lds pipelines always drain-serialize).
// W(s+2) reg-loads issued before the raw s_barrier stay in flight across it.
// A never touches LDS: direct global->reg fragments from the L2-resident
// 2.6 MB bf16 slab. One lgkmcnt(0)+s_barrier per super-step (17 barriers
// total). No K-split: W read exactly once, no partials, no reduce pass.
//
// Stage 0: cvt x,y f32 -> bf16
// Stage 1+2: qk GEMM: BM=320, BN=32, K=4096 = 16 supers of 256.
//   grid 256 = 1 block/CU; z pinned to XCD half via blockIdx&7.
// Stage 3: kkt = SCALE * k.k^T per (b,h)      (bf16)
// Stage 4: out = softplus(SCALE * qT @ kkt^T) (f32)

typedef __attribute__((ext_vector_type(4))) float  f32x4;
typedef __attribute__((ext_vector_type(8))) __bf16 bf16x8;
typedef __attribute__((ext_vector_type(4))) __bf16 bf16x4;

#define SCALE 0.03125f

static __device__ __forceinline__ f32x4 mfma16(bf16x8 a, bf16x8 b, f32x4 c) {
    return __builtin_amdgcn_mfma_f32_16x16x32_bf16(a, b, c, 0, 0, 0);
}

static __device__ __forceinline__ bf16x8 pack8(f32x4 a, f32x4 b) {
    bf16x8 r;
    #pragma unroll
    for (int i = 0; i < 4; ++i) { r[i] = (__bf16)a[i]; r[4 + i] = (__bf16)b[i]; }
    return r;
}

static __device__ __forceinline__ float softplus(float x) {
    return fmaxf(x, 0.0f) + log1pf(expf(-fabsf(x)));
}

// ---------------------------------------------------------------------------
// Stage 0: f32 -> bf16 conversion of activations. grid (640, 2), 256 thr.
// ---------------------------------------------------------------------------
__global__ __launch_bounds__(256)
void cvt_kernel(const float* __restrict__ x, const float* __restrict__ y,
                __bf16* __restrict__ xb, __bf16* __restrict__ yb)
{
    const float* src = blockIdx.y ? y : x;
    __bf16* dst = blockIdx.y ? yb : xb;
    size_t i = ((size_t)blockIdx.x * 256 + threadIdx.x) * 8;
    f32x4 a = *(const f32x4*)(src + i);
    f32x4 b = *(const f32x4*)(src + i + 4);
    *(bf16x8*)(dst + i) = pack8(a, b);
}

// ---------------------------------------------------------------------------
// Stage 1+2: C(320x4096) = A(320x4096,bf16) @ W^T. BN=32, full K per block.
// grid 256: key=blockIdx&7=(z<<2)|(panel&3); panel=(blockIdx>>3)*4+(key&3).
// 256 thr = 4 waves; wave tile 80 rows x 32 cols, acc[5][2] (40 VGPR).
// Per super (K=256 f32): each wave reg-loads its 8 W rows as ONE f32x4 per
// lane per row (1 KB contiguous per instruction), converts to bf16 and
// ds_writes into the double-buffered 16 KB W tile. Swizzle: phys 16B slot
// = logical slot ^ (row&7), applied on write AND read (2-way max).
// A fragments: direct global->reg from the XCD-L2-resident slab.
// ---------------------------------------------------------------------------
__global__ __launch_bounds__(256, 2)
void qk_gemm(const __bf16* __restrict__ yb, const __bf16* __restrict__ xb,
             const float* __restrict__ Wq, const float* __restrict__ Wk,
             __bf16* __restrict__ qT, __bf16* __restrict__ kout)
{
    const int key   = blockIdx.x & 7;
    const int z     = key >> 2;
    const int panel = ((blockIdx.x >> 3) << 2) + (key & 3);   // 0..127
    const int bn    = panel * 32;

    __shared__ __bf16 lW[2][32 * 256];    // 16 KB per buffer

    const int tid  = threadIdx.x;
    const int lane = tid & 63;
    const int wid  = tid >> 6;            // 0..3
    const int li   = lane & 15;
    const int lk   = lane >> 4;

    const __bf16* __restrict__ Ab = z ? xb : yb;   // [320][4096] bf16
    const float*  __restrict__ Wm = z ? Wk : Wq;

    // A fragment pointers: row = wid*80 + m*16 + li, k-offset lk*8
    const __bf16* ap[5];
    #pragma unroll
    for (int m = 0; m < 5; ++m)
        ap[m] = Ab + (size_t)(wid * 80 + m * 16 + li) * 4096 + lk * 8;

    // W staging: wave wid owns rows wid*8+i (i=0..7); lane reads f32x4 at
    // f32-col lane*4 -> one instruction = 1 KB contiguous of one W row.
    const float* wg = Wm + (size_t)(bn + wid * 8) * 4096 + lane * 4;

    // ds_write address for row r: byte = r*512 + (((lane>>1)^(r&7))<<4)
    //                                   + (lane&1)*8   (bf16x4 per lane)
    int wdst[8];
    #pragma unroll
    for (int i = 0; i < 8; ++i) {
        const int r = wid * 8 + i;
        wdst[i] = r * 512 + (((lane >> 1) ^ (r & 7)) << 4) + ((lane & 1) << 3);
    }

    f32x4 acc[5][2] = {};
    f32x4 wreg[8];

#define WLOAD(SUP)                                                             \
    _Pragma("unroll")                                                          \
    for (int i = 0; i < 8; ++i)                                                \
        wreg[i] = __builtin_nontemporal_load(                                  \
            (const f32x4*)(wg + (size_t)i * 4096 + (SUP) * 256));

#define WSTORE(BUF)                                                            \
    _Pragma("unroll")                                                          \
    for (int i = 0; i < 8; ++i) {                                              \
        bf16x4 v; v[0] = (__bf16)wreg[i][0]; v[1] = (__bf16)wreg[i][1];        \
                  v[2] = (__bf16)wreg[i][2]; v[3] = (__bf16)wreg[i][3];        \
        *(bf16x4*)((char*)&lW[BUF][0] + wdst[i]) = v;                          \
    }

    // prologue: W(0) -> buf0; issue W(1)
    WLOAD(0);
    WSTORE(0);                            // compiler waits wreg automatically
    WLOAD(1);
    asm volatile("s_waitcnt lgkmcnt(0)" ::: "memory");
    __builtin_amdgcn_s_barrier();
    __builtin_amdgcn_sched_barrier(0);

    for (int s = 0; s < 16; ++s) {
        const __bf16* LB = lW[s & 1];

        #pragma unroll
        for (int sl = 0; sl < 8; ++sl) {
            bf16x8 af[5];
            #pragma unroll
            for (int m = 0; m < 5; ++m)
                af[m] = *(const bf16x8*)(ap[m] + s * 256 + sl * 32);
            bf16x8 wf[2];
            #pragma unroll
            for (int jn = 0; jn < 2; ++jn) {
                const int j    = jn * 16 + li;
                const int slot = (sl * 4 + lk) ^ (j & 7);
                wf[jn] = *(const bf16x8*)((const char*)LB + j * 512 + (slot << 4));
            }
            __builtin_amdgcn_s_setprio(1);
            #pragma unroll
            for (int m = 0; m < 5; ++m) {
                acc[m][0] = mfma16(af[m], wf[0], acc[m][0]);
                acc[m][1] = mfma16(af[m], wf[1], acc[m][1]);
            }
            __builtin_amdgcn_s_setprio(0);
        }

        if (s < 15) {
            WSTORE((s + 1) & 1);          // wreg holds W(s+1); auto vmcnt wait
            if (s < 14) WLOAD(s + 2);     // in flight across the barrier
            asm volatile("s_waitcnt lgkmcnt(0)" ::: "memory");
            __builtin_amdgcn_s_barrier();
            __builtin_amdgcn_sched_barrier(0);
        }
    }
#undef WLOAD
#undef WSTORE

    // Epilogue. C/D layout: col = li, row = lk*4 + r.
    if (z == 0) {
        #pragma unroll
        for (int m = 0; m < 5; ++m) {
            const int row0 = wid * 80 + m * 16 + lk * 4;   // never straddles 160
            const int b  = row0 >= 160;
            const int ri = row0 - b * 160;
            #pragma unroll
            for (int jn = 0; jn < 2; ++jn) {
                const int col = bn + jn * 16 + li;
                bf16x4 v;
                #pragma unroll
                for (int r = 0; r < 4; ++r) v[r] = (__bf16)acc[m][jn][r];
                *(bf16x4*)(qT + (size_t)b * 4096 * 160 + (size_t)col * 160 + ri) = v;
            }
        }
    } else {
        #pragma unroll
        for (int m = 0; m < 5; ++m) {
            const int row0 = wid * 80 + m * 16 + lk * 4;
            #pragma unroll
            for (int jn = 0; jn < 2; ++jn) {
                const int col = bn + jn * 16 + li;
                #pragma unroll
                for (int r = 0; r < 4; ++r)
                    kout[(size_t)(row0 + r) * 4096 + col] = (__bf16)acc[m][jn][r];
            }
        }
    }
}

// ---------------------------------------------------------------------------
// Stage 3: kkt (symmetric). One wave per 16x16 output tile, K=1024.
// ---------------------------------------------------------------------------
__global__ __launch_bounds__(64)
void kkt_kernel(const __bf16* __restrict__ kmat, __bf16* __restrict__ kkt)
{
    const int bh = blockIdx.x;            // b*4 + h
    const int b  = bh >> 2, h = bh & 3;
    const int i0 = blockIdx.y * 16;
    const int j0 = blockIdx.z * 16;
    const int lane = threadIdx.x;

    const __bf16* base = kmat + (size_t)b * 160 * 4096 + h * 1024;
    const int ko = (lane >> 4) << 3;
    const __bf16* pa = base + (size_t)(i0 + (lane & 15)) * 4096 + ko;
    const __bf16* pb = base + (size_t)(j0 + (lane & 15)) * 4096 + ko;

    f32x4 acc = {};
    #pragma unroll 4
    for (int kk = 0; kk < 1024; kk += 32) {
        bf16x8 a  = *(const bf16x8*)(pa + kk);
        bf16x8 bb = *(const bf16x8*)(pb + kk);
        acc = mfma16(a, bb, acc);
    }

    #pragma unroll
    for (int r = 0; r < 4; ++r) {
        int i = i0 + ((lane >> 4) << 2) + r;
        int j = j0 + (lane & 15);
        kkt[((size_t)bh * 160 + i) * 160 + j] = (__bf16)(acc[r] * SCALE);
    }
}

// ---------------------------------------------------------------------------
// Stage 4: dots + softplus. Per (b,h): C(4096x160) = qT[b] @ kkt[b,h]^T.
// K=160, full j-range per block (acc[10]); grid (64 i-tiles, 8 bh).
// ---------------------------------------------------------------------------
__global__ __launch_bounds__(256)
void dots_kernel(const __bf16* __restrict__ qT, const __bf16* __restrict__ kkt,
                 float* __restrict__ out)
{
    const int bh   = blockIdx.y;
    const int b    = bh >> 2;
    const int lane = threadIdx.x & 63;
    const int wid  = threadIdx.x >> 6;
    const int li   = lane & 15;
    const int lk   = lane >> 4;
    const int i0   = blockIdx.x * 64 + wid * 16;

    const __bf16* pa = qT + (size_t)b * 4096 * 160 + (size_t)(i0 + li) * 160 + lk * 8;
    const __bf16* pb = kkt + (size_t)bh * 160 * 160 + (size_t)li * 160 + lk * 8;

    f32x4 acc[10] = {};
    #pragma unroll
    for (int m0 = 0; m0 < 160; m0 += 32) {
        bf16x8 a = *(const bf16x8*)(pa + m0);
        #pragma unroll
        for (int jn = 0; jn < 10; ++jn) {
            bf16x8 bb = *(const bf16x8*)(pb + jn * 16 * 160 + m0);
            acc[jn] = mfma16(a, bb, acc[jn]);
        }
    }

    #pragma unroll
    for (int jn = 0; jn < 10; ++jn) {
        const int j = jn * 16 + li;
        #pragma unroll
        for (int r = 0; r < 4; ++r) {
            const int i = i0 + lk * 4 + r;
            out[((size_t)bh * 4096 + i) * 160 + j] = softplus(acc[jn][r] * SCALE);
        }
    }
}

// ---------------------------------------------------------------------------
extern "C" void kernel_launch(void* const* d_in, const int* in_sizes, int n_in,
                              void* d_out, int out_size, void* d_ws, size_t ws_size,
                              hipStream_t stream)
{
    const float* x  = (const float*)d_in[0];
    const float* y  = (const float*)d_in[1];
    const float* Wq = (const float*)d_in[2];
    const float* Wk = (const float*)d_in[3];
    float* out = (float*)d_out;

    // ws (bf16): qT[2*4096*160], k[320*4096], kkt[8*160*160],
    //            xb[320*4096], yb[320*4096]   (~10.9 MB)
    __bf16* qT  = (__bf16*)d_ws;
    __bf16* kbf = qT  + (size_t)2 * 4096 * 160;
    __bf16* kkt = kbf + (size_t)320 * 4096;
    __bf16* xb  = kkt + (size_t)8 * 160 * 160;
    __bf16* yb  = xb  + (size_t)320 * 4096;

    cvt_kernel <<<dim3(640, 2),    256, 0, stream>>>(x, y, xb, yb);
    qk_gemm    <<<dim3(256),       256, 0, stream>>>(yb, xb, Wq, Wk, qT, kbf);
    kkt_kernel <<<dim3(8, 10, 10),  64, 0, stream>>>(kbf, kkt);
    dots_kernel<<<dim3(64, 8),     256, 0, stream>>>(qT, kkt, out);
}